// Round 2
// baseline (101.373 us; speedup 1.0000x reference)
//
#include <hip/hip_runtime.h>

#define N 1024
#define E 256
#define H 128

typedef _Float16 hv2 __attribute__((ext_vector_type(2)));
typedef _Float16 half_t;

__device__ __forceinline__ float dot2_acc(hv2 a, hv2 b, float c) {
#if __has_builtin(__builtin_amdgcn_fdot2)
    return __builtin_amdgcn_fdot2(a, b, c, false);
#else
    return c + (float)a.x * (float)b.x + (float)a.y * (float)b.y;
#endif
}

__device__ __forceinline__ hv2 relu_add2(hv2 a, hv2 b) {
    hv2 s = a + b;
    hv2 z = (hv2)(_Float16)0.f;
    return __builtin_elementwise_max(s, z);
}

// Setup: blocks 0..255 compute Wq' = Wq@W1a, Wk' = Wk@W1b (one row each).
// Block 256 computes ctx = relu(x@Wc+bc), then constq=(bq+ctx)@W1a+b1,
// constk=(bk+ctx)@W1b.
__global__ __launch_bounds__(256) void setup_kernel(
    const float* __restrict__ x, const float* __restrict__ Wc, const float* __restrict__ bc,
    const float* __restrict__ Wq, const float* __restrict__ bq,
    const float* __restrict__ Wk, const float* __restrict__ bk,
    const float* __restrict__ W1, const float* __restrict__ b1,
    float* __restrict__ Wqp, float* __restrict__ Wkp,
    float* __restrict__ constq, float* __restrict__ constk) {
    int b = blockIdx.x;
    int t = threadIdx.x;
    if (b < E) {
        __shared__ float wq_s[H], wk_s[H];
        if (t < H) wq_s[t] = Wq[b * H + t];
        else       wk_s[t - H] = Wk[b * H + (t - H)];
        __syncthreads();
        int h = t & (H - 1);
        float acc = 0.f;
        if (t < H) {
#pragma unroll 8
            for (int r = 0; r < H; ++r) acc += wq_s[r] * W1[r * H + h];
            Wqp[b * H + h] = acc;
        } else {
#pragma unroll 8
            for (int r = 0; r < H; ++r) acc += wk_s[r] * W1[(H + r) * H + h];
            Wkp[b * H + h] = acc;
        }
    } else {
        __shared__ float xs[E];
        __shared__ float pc[2][H];
        __shared__ float aq_s[H], ak_s[H];
        xs[t] = x[t];
        __syncthreads();
        int h = t & (H - 1);
        int c = t >> 7;  // 0 or 1
        float p = 0.f;
#pragma unroll 8
        for (int e = c * H; e < c * H + H; ++e) p += xs[e] * Wc[e * H + h];
        pc[c][h] = p;
        __syncthreads();
        if (t < H) {
            float ctxv = fmaxf(pc[0][t] + pc[1][t] + bc[t], 0.f);
            aq_s[t] = bq[t] + ctxv;
            ak_s[t] = bk[t] + ctxv;
        }
        __syncthreads();
        float acc;
        if (t < H) {
            acc = b1[h];
#pragma unroll 8
            for (int r = 0; r < H; ++r) acc += aq_s[r] * W1[r * H + h];
            constq[h] = acc;
        } else {
            acc = 0.f;
#pragma unroll 8
            for (int r = 0; r < H; ++r) acc += ak_s[r] * W1[(H + r) * H + h];
            constk[h] = acc;
        }
    }
}

// proj: 2 rows per block (512 blocks -> 2 blocks/CU, 2 waves/SIMD for latency
// hiding; was 4 rows/256 blocks = 1 wave/SIMD). e-loop unrolled x8 so 8
// independent Wqp/Wkp column loads are in flight per batch.
__global__ __launch_bounds__(256) void proj_kernel(
    const float* __restrict__ P,
    const float* __restrict__ Wqp, const float* __restrict__ Wkp,
    const float* __restrict__ constq, const float* __restrict__ constk,
    half_t* __restrict__ qh, half_t* __restrict__ kh) {
    __shared__ __align__(16) float p_s[2 * E];
    int b = blockIdx.x;
    int i0 = b * 2;
    int t = threadIdx.x;
    if (t < 128) ((float4*)p_s)[t] = ((const float4*)(P + i0 * E))[t];
    __syncthreads();
    bool isq = t < H;
    int h = t & (H - 1);
    const float* M = isq ? Wqp : Wkp;
    float cv = isq ? constq[h] : constk[h];
    float a0 = cv, a1 = cv;
    for (int e = 0; e < E; e += 8) {
        float m0 = M[(e + 0) * H + h];
        float m1 = M[(e + 1) * H + h];
        float m2 = M[(e + 2) * H + h];
        float m3 = M[(e + 3) * H + h];
        float m4 = M[(e + 4) * H + h];
        float m5 = M[(e + 5) * H + h];
        float m6 = M[(e + 6) * H + h];
        float m7 = M[(e + 7) * H + h];
        float4 p0a = *(const float4*)&p_s[0 * E + e];
        float4 p0b = *(const float4*)&p_s[0 * E + e + 4];
        float4 p1a = *(const float4*)&p_s[1 * E + e];
        float4 p1b = *(const float4*)&p_s[1 * E + e + 4];
        a0 += p0a.x * m0 + p0a.y * m1 + p0a.z * m2 + p0a.w * m3
            + p0b.x * m4 + p0b.y * m5 + p0b.z * m6 + p0b.w * m7;
        a1 += p1a.x * m0 + p1a.y * m1 + p1a.z * m2 + p1a.w * m3
            + p1b.x * m4 + p1b.y * m5 + p1b.z * m6 + p1b.w * m7;
    }
    half_t* O = isq ? qh : kh;
    O[(i0 + 0) * H + h] = (half_t)a0;
    O[(i0 + 1) * H + h] = (half_t)a1;
}

// pair: exact triangular tiling. 528 blocks, one 32x32 (bi<=bj) tile each.
// Per thread: 4 (i,j) pairs; f16 LDS + fdot2.
#define QSTR 136  // halves; 272 B row stride -> odd count of 16B superbanks -> conflict-free b128
#define NTILE 32  // 32 row-tiles of 32
__global__ __launch_bounds__(256) void pair_kernel(
    const half_t* __restrict__ qh, const half_t* __restrict__ kh,
    const float* __restrict__ W2, const float* __restrict__ b2,
    float* __restrict__ out) {
    // map linear tile id -> (bi, bj), bi <= bj, row-major upper-tri incl diag
    int tid = blockIdx.x;
    int bi = (int)((65.0f - sqrtf(4225.0f - 8.0f * (float)tid)) * 0.5f);
    // fixup against fp error: base(bi) = 32*bi - bi*(bi-1)/2
    while (bi > 0 && tid < 32 * bi - bi * (bi - 1) / 2) --bi;
    while (tid >= 32 * (bi + 1) - (bi + 1) * bi / 2) ++bi;
    int bj = bi + (tid - (32 * bi - bi * (bi - 1) / 2));

    __shared__ __align__(16) half_t qs[32][QSTR];
    __shared__ __align__(16) half_t ks[32][QSTR];
    __shared__ __align__(16) half_t w2s[H];

    int t = threadIdx.x;
    if (t < H) w2s[t] = (half_t)W2[t];

    const float4* qh4 = (const float4*)(qh + bi * 32 * H);
    const float4* kh4 = (const float4*)(kh + bj * 32 * H);
#pragma unroll
    for (int v = 0; v < 2; ++v) {
        int idx = v * 256 + t;           // 0..511 : 32 rows x 16 float4
        int r = idx >> 4, c = idx & 15;
        float4 q = qh4[idx];
        float4 k = kh4[idx];
        *(float4*)&qs[r][c * 8] = q;
        *(float4*)&ks[r][c * 8] = k;
    }
    __syncthreads();

    int jj  = t & 31;    // k row within tile
    int ti0 = t >> 5;    // q rows ti0, ti0+8, ti0+16, ti0+24
    float b2v = b2[0];
    float acc[4];
#pragma unroll
    for (int u = 0; u < 4; ++u) acc[u] = b2v;

    for (int h8 = 0; h8 < 16; ++h8) {
        float4 wf = *(const float4*)&w2s[h8 * 8];
        float4 kv = *(const float4*)&ks[jj][h8 * 8];
        const hv2* wp = (const hv2*)&wf;
        const hv2* kp2 = (const hv2*)&kv;
#pragma unroll
        for (int u = 0; u < 4; ++u) {
            float4 qf = *(const float4*)&qs[ti0 + u * 8][h8 * 8];
            const hv2* qp2 = (const hv2*)&qf;
#pragma unroll
            for (int s = 0; s < 4; ++s) {
                hv2 sa = relu_add2(qp2[s], kp2[s]);
                acc[u] = dot2_acc(sa, wp[s], acc[u]);
            }
        }
    }

#pragma unroll
    for (int u = 0; u < 4; ++u) {
        int i = bi * 32 + ti0 + u * 8;
        int j = bj * 32 + jj;
        if (j > i) {
            int base = i * (2 * N - i - 1) / 2;
            out[base + (j - i - 1)] = acc[u];
        }
    }
}

extern "C" void kernel_launch(void* const* d_in, const int* in_sizes, int n_in,
                              void* d_out, int out_size, void* d_ws, size_t ws_size,
                              hipStream_t stream) {
    const float* x  = (const float*)d_in[0];
    const float* P  = (const float*)d_in[1];
    const float* Wq = (const float*)d_in[2];
    const float* bq = (const float*)d_in[3];
    const float* Wk = (const float*)d_in[4];
    const float* bk = (const float*)d_in[5];
    const float* Wc = (const float*)d_in[6];
    const float* bc = (const float*)d_in[7];
    const float* W1 = (const float*)d_in[8];
    const float* b1 = (const float*)d_in[9];
    const float* W2 = (const float*)d_in[10];
    const float* b2 = (const float*)d_in[11];
    float* out = (float*)d_out;

    float* ws     = (float*)d_ws;
    float* constq = ws;                      // 128
    float* constk = ws + H;                  // 128
    float* Wqp    = ws + 2 * H;              // 256*128
    float* Wkp    = Wqp + E * H;             // 256*128
    half_t* qh    = (half_t*)(Wkp + E * H);  // 1024*128 halves
    half_t* kh    = qh + N * H;              // 1024*128 halves

    setup_kernel<<<E + 1, 256, 0, stream>>>(x, Wc, bc, Wq, bq, Wk, bk, W1, b1,
                                            Wqp, Wkp, constq, constk);
    proj_kernel<<<N / 2, 256, 0, stream>>>(P, Wqp, Wkp, constq, constk, qh, kh);
    pair_kernel<<<528, 256, 0, stream>>>(qh, kh, W2, b2, out);
}